// Round 1
// baseline (1990.810 us; speedup 1.0000x reference)
//
#include <hip/hip_runtime.h>
#include <stdint.h>
#include <math.h>

typedef unsigned int u32;

#define BB 4096
#define DD 256
#define KK 512
#define LL 32768
#define QQ 8192

// ---------------- Threefry2x32 (JAX-exact, 20 rounds) ----------------
__host__ __device__ inline void tf2x32(u32 k0, u32 k1, u32 c0, u32 c1, u32& o0, u32& o1) {
  u32 ks2 = k0 ^ k1 ^ 0x1BD11BDAu;
  u32 x0 = c0 + k0, x1 = c1 + k1;
#define TF_R(r) { x0 += x1; x1 = ((x1 << (r)) | (x1 >> (32 - (r)))); x1 ^= x0; }
  TF_R(13) TF_R(15) TF_R(26) TF_R(6)
  x0 += k1; x1 += ks2 + 1u;
  TF_R(17) TF_R(29) TF_R(16) TF_R(24)
  x0 += ks2; x1 += k0 + 2u;
  TF_R(13) TF_R(15) TF_R(26) TF_R(6)
  x0 += k0; x1 += k1 + 3u;
  TF_R(17) TF_R(29) TF_R(16) TF_R(24)
  x0 += k1; x1 += ks2 + 4u;
  TF_R(13) TF_R(15) TF_R(26) TF_R(6)
  x0 += ks2; x1 += k0 + 5u;
#undef TF_R
  o0 = x0; o1 = x1;
}

// partitionable-mode random bits: xor of the two cipher outputs at counter (0, i)
__device__ inline u32 rbits32(u32 k0, u32 k1, u32 i) {
  u32 a, b;
  tf2x32(k0, k1, 0u, i, a, b);
  return a ^ b;
}

__device__ inline float u01f(u32 bits) {
  return __uint_as_float(0x3f800000u | (bits >> 9)) - 1.0f;
}

// gumbel(-log(-log(u))), u = uniform(1e-20, 1.0) per JAX formula
__device__ inline float gumbel_at(u32 k0, u32 k1, u32 i) {
  float f = u01f(rbits32(k0, k1, i));
  float u = fmaxf(1e-20f, f + 1e-20f);   // f*(1-1e-20)+1e-20 with (1-1e-20)==1 in f32
  float l1 = (float)log((double)u);       // correctly-rounded f32 log
  float l2 = (float)log((double)(-l1));
  return -l2;
}

// XLA f32 ErfInv (Giles polynomial)
__device__ inline float erfinv32(float x) {
  float w = -log1pf(-x * x);
  float p;
  if (w < 5.0f) {
    w -= 2.5f;
    p = 2.81022636e-08f;
    p = fmaf(p, w, 3.43273939e-07f);
    p = fmaf(p, w, -3.5233877e-06f);
    p = fmaf(p, w, -4.39150654e-06f);
    p = fmaf(p, w, 0.00021858087f);
    p = fmaf(p, w, -0.00125372503f);
    p = fmaf(p, w, -0.00417768164f);
    p = fmaf(p, w, 0.246640727f);
    p = fmaf(p, w, 1.50140941f);
  } else {
    w = sqrtf(w) - 3.0f;
    p = -0.000200214257f;
    p = fmaf(p, w, 0.000100950558f);
    p = fmaf(p, w, 0.00134934322f);
    p = fmaf(p, w, -0.00367342844f);
    p = fmaf(p, w, 0.00573950773f);
    p = fmaf(p, w, -0.0076224613f);
    p = fmaf(p, w, 0.00943887047f);
    p = fmaf(p, w, 1.00167406f);
    p = fmaf(p, w, 2.83297682f);
  }
  return p * x;
}

// ---------------- Reductions ----------------
__global__ __launch_bounds__(256)
void k_sumsq(const float* __restrict__ x, int n, float* __restrict__ partial) {
  __shared__ float sm[256];
  float s = 0.0f;
  for (int i = blockIdx.x * 256 + threadIdx.x; i < n; i += gridDim.x * 256) {
    float v = x[i]; s = fmaf(v, v, s);
  }
  sm[threadIdx.x] = s; __syncthreads();
  for (int off = 128; off > 0; off >>= 1) {
    if (threadIdx.x < off) sm[threadIdx.x] += sm[threadIdx.x + off];
    __syncthreads();
  }
  if (threadIdx.x == 0) partial[blockIdx.x] = sm[0];
}

__global__ __launch_bounds__(256)
void k_finalize_rsqrt(const float* __restrict__ partial, float* __restrict__ outv) {
  __shared__ float sm[256];
  int tid = threadIdx.x;
  sm[tid] = partial[tid];
  __syncthreads();
  for (int off = 128; off > 0; off >>= 1) {
    if (tid < off) sm[tid] += sm[tid + off];
    __syncthreads();
  }
  if (tid == 0) {
    float ssum = fmaxf(sm[0], 1e-12f);
    outv[0] = (float)(1.0 / sqrt((double)ssum));
  }
}

// ---------------- GEMMs (simple 16x16 tiled, D inner fixed 256 for NT) ----------------
__global__ __launch_bounds__(256)
void k_gemm_nt(const float* __restrict__ A, const float* __restrict__ Bm,
               float* __restrict__ C, int M, int N) {
  // C[i][j] = dot(A[i][:256], Bm[j][:256])
  __shared__ float As[16][17], Bs[16][17];
  int tx = threadIdx.x, ty = threadIdx.y;
  int i = blockIdx.y * 16 + ty;
  int j = blockIdx.x * 16 + tx;
  float acc = 0.0f;
  for (int kt = 0; kt < 256; kt += 16) {
    As[ty][tx] = A[i * 256 + kt + tx];
    Bs[ty][tx] = Bm[(blockIdx.x * 16 + ty) * 256 + kt + tx];
    __syncthreads();
#pragma unroll
    for (int kk = 0; kk < 16; kk++)
      acc = fmaf(As[ty][kk], Bs[tx][kk], acc);
    __syncthreads();
  }
  C[i * N + j] = acc;
}

__global__ __launch_bounds__(256)
void k_gemm_nn(const float* __restrict__ A, const float* __restrict__ Bm,
               float* __restrict__ C, int M, int N, int Kd) {
  __shared__ float As[16][17], Bs[16][17];
  int tx = threadIdx.x, ty = threadIdx.y;
  int i = blockIdx.y * 16 + ty;
  int j = blockIdx.x * 16 + tx;
  float acc = 0.0f;
  for (int kt = 0; kt < Kd; kt += 16) {
    As[ty][tx] = A[i * Kd + kt + tx];
    Bs[ty][tx] = Bm[(kt + ty) * N + j];
    __syncthreads();
#pragma unroll
    for (int kk = 0; kk < 16; kk++)
      acc = fmaf(As[ty][kk], Bs[kk][tx], acc);
    __syncthreads();
  }
  C[i * N + j] = acc;
}

// ---------------- softmax(y1) + hard argmax(y2) per row ----------------
__global__ __launch_bounds__(256)
void k_softmax_assign(const float* __restrict__ knT, float* __restrict__ Y,
                      float* __restrict__ assignOut,
                      u32 g1a, u32 g1b, u32 g2a, u32 g2b) {
  __shared__ float red[256];
  __shared__ int redi[256];
  int b = blockIdx.x, tid = threadIdx.x;
  int i0 = b * KK + tid, i1 = i0 + 256;
  float x0 = knT[i0], x1 = knT[i1];

  // soft assignment y1
  float z0 = x0 + gumbel_at(g1a, g1b, (u32)i0);
  float z1 = x1 + gumbel_at(g1a, g1b, (u32)i1);
  red[tid] = fmaxf(z0, z1); __syncthreads();
  for (int off = 128; off > 0; off >>= 1) {
    if (tid < off) red[tid] = fmaxf(red[tid], red[tid + off]);
    __syncthreads();
  }
  float m = red[0]; __syncthreads();
  float e0 = expf(z0 - m), e1 = expf(z1 - m);
  red[tid] = e0 + e1; __syncthreads();
  for (int off = 128; off > 0; off >>= 1) {
    if (tid < off) red[tid] += red[tid + off];
    __syncthreads();
  }
  float s = red[0]; __syncthreads();
  Y[i0] = e0 / s;
  Y[i1] = e1 / s;

  if (assignOut != nullptr) {
    // mimic argmax(softmax(z2)) exactly, including division rounding + first-index ties
    float w0 = x0 + gumbel_at(g2a, g2b, (u32)i0);
    float w1 = x1 + gumbel_at(g2a, g2b, (u32)i1);
    red[tid] = fmaxf(w0, w1); __syncthreads();
    for (int off = 128; off > 0; off >>= 1) {
      if (tid < off) red[tid] = fmaxf(red[tid], red[tid + off]);
      __syncthreads();
    }
    float m2 = red[0]; __syncthreads();
    float f0 = expf(w0 - m2), f1 = expf(w1 - m2);
    red[tid] = f0 + f1; __syncthreads();
    for (int off = 128; off > 0; off >>= 1) {
      if (tid < off) red[tid] += red[tid + off];
      __syncthreads();
    }
    float s2 = red[0]; __syncthreads();
    float y0 = f0 / s2, y1v = f1 / s2;
    float bv; int bi;
    if (y1v > y0) { bv = y1v; bi = tid + 256; } else { bv = y0; bi = tid; }
    red[tid] = bv; redi[tid] = bi; __syncthreads();
    for (int off = 128; off > 0; off >>= 1) {
      if (tid < off) {
        float ov = red[tid + off]; int oi = redi[tid + off];
        if (ov > red[tid] || (ov == red[tid] && oi < redi[tid])) { red[tid] = ov; redi[tid] = oi; }
      }
      __syncthreads();
    }
    if (tid == 0) assignOut[b] = (float)redi[0];
  }
}

// ---------------- stochastic binary threshold ----------------
__global__ __launch_bounds__(256)
void k_binary(const float* __restrict__ knT, float* __restrict__ BIN, u32 k3a, u32 k3b) {
  int i = blockIdx.x * 256 + threadIdx.x;   // over [K,B]
  if (i >= KK * BB) return;
  int k = i / BB, b = i - k * BB;
  float x = knT[b * KK + k];
  float prob = (float)(1.0 / (1.0 + exp(-(double)x)));
  float eps = u01f(rbits32(k3a, k3b, (u32)i));
  BIN[i] = (prob > eps) ? 1.0f : 0.0f;
}

__global__ __launch_bounds__(256)
void k_rowsum(const float* __restrict__ BIN, float* __restrict__ rs) {
  __shared__ float sm[256];
  int k = blockIdx.x, tid = threadIdx.x;
  float s = 0.0f;
  for (int b = tid; b < BB; b += 256) s += BIN[k * BB + b];
  sm[tid] = s; __syncthreads();
  for (int off = 128; off > 0; off >>= 1) {
    if (tid < off) sm[tid] += sm[tid + off];
    __syncthreads();
  }
  if (tid == 0) rs[k] = sm[0];
}

__global__ __launch_bounds__(256)
void k_divrows(float* __restrict__ AGGK, const float* __restrict__ rs) {
  int i = blockIdx.x * 256 + threadIdx.x;   // K*D
  int k = i >> 8;
  AGGK[i] = AGGK[i] / (rs[k] + 1e-8f);
}

__global__ __launch_bounds__(256)
void k_scale(float* __restrict__ x, const float* __restrict__ fac, int n) {
  int i = blockIdx.x * 256 + threadIdx.x;
  if (i < n) x[i] = x[i] * fac[0];
}

// ---------------- queue = 2*qk + 0.1*normal ----------------
__global__ __launch_bounds__(256)
void k_queue(const float* __restrict__ qk_in, const float* __restrict__ skp,
             float* __restrict__ QUEUE, u32 kqa, u32 kqb) {
  int i = blockIdx.x * 256 + threadIdx.x;   // Q*D
  if (i >= QQ * DD) return;
  float sk = skp[0];
  float qk = qk_in[i] * sk;
  float f = u01f(rbits32(kqa, kqb, (u32)i));
  const float lo = -0.99999994f;            // nextafter(-1,0)
  float u = fmaxf(lo, f * 2.0f + lo);
  float nv = 1.41421354f * erfinv32(u);     // sqrt(2)_f32 * erfinv
  float t = qk + 0.1f * nv;
  QUEUE[i] = t + qk;
}

__global__ __launch_bounds__(256)
void k_rowdot(const float* __restrict__ A, const float* __restrict__ Bv, float* __restrict__ outv) {
  __shared__ float sm[256];
  int r = blockIdx.x, tid = threadIdx.x;
  sm[tid] = A[r * 256 + tid] * Bv[r * 256 + tid];
  __syncthreads();
  for (int off = 128; off > 0; off >>= 1) {
    if (tid < off) sm[tid] += sm[tid + off];
    __syncthreads();
  }
  if (tid == 0) outv[r] = sm[0];
}

// ---------------- fused GEMM + online logsumexp ----------------
// grid: (M/64, nsplit); block 256 (16x16), 4x4 register tile; Lper = L/nsplit (mult of 64)
__global__ __launch_bounds__(256)
void k_lse_gemm(const float* __restrict__ Qm, const float* __restrict__ Negs,
                const float* __restrict__ scale_ptr, int Lper, int nsplit,
                float* __restrict__ pm, float* __restrict__ ps) {
  __shared__ float As[16][68];
  __shared__ float Bs[16][68];
  __shared__ float Ms[64][16];
  __shared__ float Ss[64][16];
  int tid = threadIdx.x;
  int tx = tid & 15, ty = tid >> 4;
  int rowBase = blockIdx.x * 64;
  int j0 = blockIdx.y * Lper;
  float lsc = scale_ptr[0] / 0.07f;
  float mloc[4], sloc[4];
#pragma unroll
  for (int r = 0; r < 4; r++) { mloc[r] = -1e30f; sloc[r] = 0.0f; }

  for (int jc = 0; jc < Lper; jc += 64) {
    float c[4][4];
#pragma unroll
    for (int r = 0; r < 4; r++)
#pragma unroll
      for (int q = 0; q < 4; q++) c[r][q] = 0.0f;

    for (int kt = 0; kt < 256; kt += 16) {
#pragma unroll
      for (int q = 0; q < 4; q++) {
        int idx = tid + 256 * q;
        int kkx = idx & 15, rr = idx >> 4;
        As[kkx][rr] = Qm[(rowBase + rr) * 256 + kt + kkx];
        Bs[kkx][rr] = Negs[(j0 + jc + rr) * 256 + kt + kkx];
      }
      __syncthreads();
#pragma unroll
      for (int kx = 0; kx < 16; kx++) {
        float4 a4 = *(const float4*)&As[kx][ty * 4];
        float4 b4 = *(const float4*)&Bs[kx][tx * 4];
        float av[4] = {a4.x, a4.y, a4.z, a4.w};
        float bv[4] = {b4.x, b4.y, b4.z, b4.w};
#pragma unroll
        for (int r = 0; r < 4; r++)
#pragma unroll
          for (int q = 0; q < 4; q++)
            c[r][q] = fmaf(av[r], bv[q], c[r][q]);
      }
      __syncthreads();
    }
#pragma unroll
    for (int r = 0; r < 4; r++) {
      float z0 = c[r][0] * lsc, z1 = c[r][1] * lsc, z2 = c[r][2] * lsc, z3 = c[r][3] * lsc;
      float mz = fmaxf(fmaxf(z0, z1), fmaxf(z2, z3));
      float mn = fmaxf(mloc[r], mz);
      float s = sloc[r] * expf(mloc[r] - mn);
      s += expf(z0 - mn) + expf(z1 - mn) + expf(z2 - mn) + expf(z3 - mn);
      mloc[r] = mn; sloc[r] = s;
    }
  }
#pragma unroll
  for (int r = 0; r < 4; r++) { Ms[ty * 4 + r][tx] = mloc[r]; Ss[ty * 4 + r][tx] = sloc[r]; }
  __syncthreads();
  if (tid < 64) {
    float m = Ms[tid][0], s = Ss[tid][0];
#pragma unroll
    for (int t = 1; t < 16; t++) {
      float m2 = Ms[tid][t], s2 = Ss[tid][t];
      float mn = fmaxf(m, m2);
      s = s * expf(m - mn) + s2 * expf(m2 - mn);
      m = mn;
    }
    int row = rowBase + tid;
    pm[row * nsplit + blockIdx.y] = m;
    ps[row * nsplit + blockIdx.y] = s;
  }
}

__global__ __launch_bounds__(256)
void k_lse_final(const float* __restrict__ pm, const float* __restrict__ ps, int nsplit,
                 const float* __restrict__ lpos, int M, float* __restrict__ outSlot) {
  __shared__ float sm[256];
  int tid = threadIdx.x;
  float acc = 0.0f;
  for (int row = tid; row < M; row += 256) {
    float m = -1e30f, s = 0.0f;
    for (int t = 0; t < nsplit; t++) {
      float m2 = pm[row * nsplit + t], s2 = ps[row * nsplit + t];
      float mn = fmaxf(m, m2);
      s = s * expf(m - mn) + s2 * expf(m2 - mn);
      m = mn;
    }
    float z0 = lpos[row] / 0.07f;
    float mn = fmaxf(m, z0);
    s = s * expf(m - mn) + expf(z0 - mn);
    m = mn;
    float lse = logf(s) + m;
    acc += (lse - z0);
  }
  sm[tid] = acc; __syncthreads();
  for (int off = 128; off > 0; off >>= 1) {
    if (tid < off) sm[tid] += sm[tid + off];
    __syncthreads();
  }
  if (tid == 0) outSlot[0] = sm[0] / (float)M;
}

__global__ void k_loss_add(const float* __restrict__ slots, float* __restrict__ outv) {
  outv[0] = slots[0] + slots[1];
}

// ---------------- launch ----------------
extern "C" void kernel_launch(void* const* d_in, const int* in_sizes, int n_in,
                              void* d_out, int out_size, void* d_ws, size_t ws_size,
                              hipStream_t stream) {
  const float* feat[2] = {(const float*)d_in[0], (const float*)d_in[1]};
  const float* ctx[2]  = {(const float*)d_in[2], (const float*)d_in[3]};
  const float* queue_n = (const float*)d_in[4];
  const float* queue_k = (const float*)d_in[5];

  float* W = (float*)d_ws;
  size_t o = 0;
  float* T     = W + o; o += (size_t)BB * KK;
  float* Yb    = W + o; o += (size_t)BB * KK;
  float* BIN   = W + o; o += (size_t)KK * BB;
  float* AGGN1 = W + o; o += (size_t)BB * DD;
  float* AGGK1 = W + o; o += (size_t)KK * DD;
  float* QUEUE = W + o; o += (size_t)QQ * DD;
  float* RS    = W + o; o += KK;
  float* PART  = W + o; o += 256;
  float* SCAL  = W + o; o += 8;
  float* PM    = W + o; o += (size_t)BB * 16;
  float* PS    = W + o; o += (size_t)BB * 16;
  float* LPOSN = W + o; o += BB;
  float* LPOSK = W + o; o += KK;
  float* LOSS  = W + o; o += 2;

  float* out = (float*)d_out;
  float* outAssign = out;
  float* outAggn2  = out + BB;
  float* outAggk2  = out + BB + (size_t)BB * DD;
  float* outLoss   = out + BB + (size_t)BB * DD + (size_t)KK * DD;

  // key derivation (partitionable-mode split): key(42) = (0,42)
  u32 kq0, kq1, kc[2][2];
  tf2x32(0u, 42u, 0u, 0u, kq0, kq1);
  tf2x32(0u, 42u, 0u, 1u, kc[0][0], kc[0][1]);
  tf2x32(0u, 42u, 0u, 2u, kc[1][0], kc[1][1]);
  u32 sub[2][3][2];
  for (int br = 0; br < 2; br++)
    for (int t = 0; t < 3; t++)
      tf2x32(kc[br][0], kc[br][1], 0u, (u32)t, sub[br][t][0], sub[br][t][1]);

  dim3 thr16(16, 16);

  // global-l2n factors for queue_n / queue_k
  k_sumsq<<<256, 256, 0, stream>>>(queue_n, LL * DD, PART);
  k_finalize_rsqrt<<<1, 256, 0, stream>>>(PART, SCAL + 0);   // sn
  k_sumsq<<<256, 256, 0, stream>>>(queue_k, QQ * DD, PART);
  k_finalize_rsqrt<<<1, 256, 0, stream>>>(PART, SCAL + 1);   // sk

  for (int br = 0; br < 2; br++) {
    float* aggn = (br == 0) ? AGGN1 : outAggn2;
    float* aggk = (br == 0) ? AGGK1 : outAggk2;
    // knT[b,k] = dot(feat_b, ctx_k)
    k_gemm_nt<<<dim3(KK / 16, BB / 16), thr16, 0, stream>>>(feat[br], ctx[br], T, BB, KK);
    k_softmax_assign<<<BB, 256, 0, stream>>>(T, Yb, br == 0 ? outAssign : nullptr,
        sub[br][0][0], sub[br][0][1], sub[br][1][0], sub[br][1][1]);
    k_binary<<<(KK * BB) / 256, 256, 0, stream>>>(T, BIN, sub[br][2][0], sub[br][2][1]);
    k_rowsum<<<KK, 256, 0, stream>>>(BIN, RS);
    k_gemm_nn<<<dim3(DD / 16, BB / 16), thr16, 0, stream>>>(Yb, ctx[br], aggn, BB, DD, KK);
    k_gemm_nn<<<dim3(DD / 16, KK / 16), thr16, 0, stream>>>(BIN, feat[br], aggk, KK, DD, BB);
    k_divrows<<<(KK * DD) / 256, 256, 0, stream>>>(aggk, RS);
    k_sumsq<<<256, 256, 0, stream>>>(aggn, BB * DD, PART);
    k_finalize_rsqrt<<<1, 256, 0, stream>>>(PART, SCAL + 3);
    k_scale<<<(BB * DD) / 256, 256, 0, stream>>>(aggn, SCAL + 3, BB * DD);
    k_sumsq<<<256, 256, 0, stream>>>(aggk, KK * DD, PART);
    k_finalize_rsqrt<<<1, 256, 0, stream>>>(PART, SCAL + 4);
    k_scale<<<(KK * DD) / 256, 256, 0, stream>>>(aggk, SCAL + 4, KK * DD);
  }

  // queue = 2*l2n(queue_k) + 0.1*normal(kq), then global-l2n factor (folded into scale)
  k_queue<<<(QQ * DD) / 256, 256, 0, stream>>>(queue_k, SCAL + 1, QUEUE, kq0, kq1);
  k_sumsq<<<256, 256, 0, stream>>>(QUEUE, QQ * DD, PART);
  k_finalize_rsqrt<<<1, 256, 0, stream>>>(PART, SCAL + 2);   // fq

  // positives
  k_rowdot<<<BB, 256, 0, stream>>>(AGGN1, outAggn2, LPOSN);
  k_rowdot<<<KK, 256, 0, stream>>>(AGGK1, outAggk2, LPOSK);

  // loss_n: negs = queue_n scaled by sn; loss_k: negs = QUEUE scaled by fq
  k_lse_gemm<<<dim3(BB / 64, 16), 256, 0, stream>>>(AGGN1, queue_n, SCAL + 0, LL / 16, 16, PM, PS);
  k_lse_final<<<1, 256, 0, stream>>>(PM, PS, 16, LPOSN, BB, LOSS + 0);
  k_lse_gemm<<<dim3(KK / 64, 32), 256, 0, stream>>>(AGGK1, QUEUE, SCAL + 2, QQ / 32, 32, PM, PS);
  k_lse_final<<<1, 256, 0, stream>>>(PM, PS, 32, LPOSK, KK, LOSS + 1);
  k_loss_add<<<1, 1, 0, stream>>>(LOSS, outLoss);
}

// Round 2
// 1330.949 us; speedup vs baseline: 1.4958x; 1.4958x over previous
//
#include <hip/hip_runtime.h>
#include <stdint.h>
#include <math.h>

typedef unsigned int u32;
typedef __attribute__((ext_vector_type(8))) short short8;
typedef __attribute__((ext_vector_type(4))) float f32x4;

#define BB 4096
#define DD 256
#define KK 512
#define LL 32768
#define QQ 8192

// ---------------- Threefry2x32 (JAX-exact, 20 rounds) ----------------
__host__ __device__ inline void tf2x32(u32 k0, u32 k1, u32 c0, u32 c1, u32& o0, u32& o1) {
  u32 ks2 = k0 ^ k1 ^ 0x1BD11BDAu;
  u32 x0 = c0 + k0, x1 = c1 + k1;
#define TF_R(r) { x0 += x1; x1 = ((x1 << (r)) | (x1 >> (32 - (r)))); x1 ^= x0; }
  TF_R(13) TF_R(15) TF_R(26) TF_R(6)
  x0 += k1; x1 += ks2 + 1u;
  TF_R(17) TF_R(29) TF_R(16) TF_R(24)
  x0 += ks2; x1 += k0 + 2u;
  TF_R(13) TF_R(15) TF_R(26) TF_R(6)
  x0 += k0; x1 += k1 + 3u;
  TF_R(17) TF_R(29) TF_R(16) TF_R(24)
  x0 += k1; x1 += ks2 + 4u;
  TF_R(13) TF_R(15) TF_R(26) TF_R(6)
  x0 += ks2; x1 += k0 + 5u;
#undef TF_R
  o0 = x0; o1 = x1;
}

__device__ inline u32 rbits32(u32 k0, u32 k1, u32 i) {
  u32 a, b;
  tf2x32(k0, k1, 0u, i, a, b);
  return a ^ b;
}

__device__ inline float u01f(u32 bits) {
  return __uint_as_float(0x3f800000u | (bits >> 9)) - 1.0f;
}

__device__ inline float gumbel_at(u32 k0, u32 k1, u32 i) {
  float f = u01f(rbits32(k0, k1, i));
  float u = fmaxf(1e-20f, f + 1e-20f);
  float l1 = (float)log((double)u);
  float l2 = (float)log((double)(-l1));
  return -l2;
}

// XLA f32 ErfInv (Giles polynomial)
__device__ inline float erfinv32(float x) {
  float w = -log1pf(-x * x);
  float p;
  if (w < 5.0f) {
    w -= 2.5f;
    p = 2.81022636e-08f;
    p = fmaf(p, w, 3.43273939e-07f);
    p = fmaf(p, w, -3.5233877e-06f);
    p = fmaf(p, w, -4.39150654e-06f);
    p = fmaf(p, w, 0.00021858087f);
    p = fmaf(p, w, -0.00125372503f);
    p = fmaf(p, w, -0.00417768164f);
    p = fmaf(p, w, 0.246640727f);
    p = fmaf(p, w, 1.50140941f);
  } else {
    w = sqrtf(w) - 3.0f;
    p = -0.000200214257f;
    p = fmaf(p, w, 0.000100950558f);
    p = fmaf(p, w, 0.00134934322f);
    p = fmaf(p, w, -0.00367342844f);
    p = fmaf(p, w, 0.00573950773f);
    p = fmaf(p, w, -0.0076224613f);
    p = fmaf(p, w, 0.00943887047f);
    p = fmaf(p, w, 1.00167406f);
    p = fmaf(p, w, 2.83297682f);
  }
  return p * x;
}

__device__ inline unsigned short f2bf(float f) {
  u32 u = __float_as_uint(f);
  u32 r = (u + 0x7FFFu + ((u >> 16) & 1u)) >> 16;
  return (unsigned short)r;
}

// ---------------- Reductions ----------------
__global__ __launch_bounds__(256)
void k_sumsq(const float* __restrict__ x, int n, float* __restrict__ partial) {
  __shared__ float sm[256];
  float s = 0.0f;
  for (int i = blockIdx.x * 256 + threadIdx.x; i < n; i += gridDim.x * 256) {
    float v = x[i]; s = fmaf(v, v, s);
  }
  sm[threadIdx.x] = s; __syncthreads();
  for (int off = 128; off > 0; off >>= 1) {
    if (threadIdx.x < off) sm[threadIdx.x] += sm[threadIdx.x + off];
    __syncthreads();
  }
  if (threadIdx.x == 0) partial[blockIdx.x] = sm[0];
}

__global__ __launch_bounds__(256)
void k_finalize_rsqrt(const float* __restrict__ partial, float* __restrict__ outv) {
  __shared__ float sm[256];
  int tid = threadIdx.x;
  sm[tid] = partial[tid];
  __syncthreads();
  for (int off = 128; off > 0; off >>= 1) {
    if (tid < off) sm[tid] += sm[tid + off];
    __syncthreads();
  }
  if (tid == 0) {
    float ssum = fmaxf(sm[0], 1e-12f);
    outv[0] = (float)(1.0 / sqrt((double)ssum));
  }
}

// ---------------- GEMMs (f32 paths kept bit-identical to R1) ----------------
__global__ __launch_bounds__(256)
void k_gemm_nt(const float* __restrict__ A, const float* __restrict__ Bm,
               float* __restrict__ C, int M, int N) {
  __shared__ float As[16][17], Bs[16][17];
  int tx = threadIdx.x, ty = threadIdx.y;
  int i = blockIdx.y * 16 + ty;
  int j = blockIdx.x * 16 + tx;
  float acc = 0.0f;
  for (int kt = 0; kt < 256; kt += 16) {
    As[ty][tx] = A[i * 256 + kt + tx];
    Bs[ty][tx] = Bm[(blockIdx.x * 16 + ty) * 256 + kt + tx];
    __syncthreads();
#pragma unroll
    for (int kk = 0; kk < 16; kk++)
      acc = fmaf(As[ty][kk], Bs[tx][kk], acc);
    __syncthreads();
  }
  C[i * N + j] = acc;
}

__global__ __launch_bounds__(256)
void k_gemm_nn(const float* __restrict__ A, const float* __restrict__ Bm,
               float* __restrict__ C, int M, int N, int Kd) {
  __shared__ float As[16][17], Bs[16][17];
  int tx = threadIdx.x, ty = threadIdx.y;
  int i = blockIdx.y * 16 + ty;
  int j = blockIdx.x * 16 + tx;
  float acc = 0.0f;
  for (int kt = 0; kt < Kd; kt += 16) {
    As[ty][tx] = A[i * Kd + kt + tx];
    Bs[ty][tx] = Bm[(kt + ty) * N + j];
    __syncthreads();
#pragma unroll
    for (int kk = 0; kk < 16; kk++)
      acc = fmaf(As[ty][kk], Bs[kk][tx], acc);
    __syncthreads();
  }
  C[i * N + j] = acc;
}

// ---------------- softmax(y1) + hard argmax(y2) per row ----------------
__global__ __launch_bounds__(256)
void k_softmax_assign(const float* __restrict__ knT, float* __restrict__ Y,
                      float* __restrict__ assignOut,
                      u32 g1a, u32 g1b, u32 g2a, u32 g2b) {
  __shared__ float red[256];
  __shared__ int redi[256];
  int b = blockIdx.x, tid = threadIdx.x;
  int i0 = b * KK + tid, i1 = i0 + 256;
  float x0 = knT[i0], x1 = knT[i1];

  float z0 = x0 + gumbel_at(g1a, g1b, (u32)i0);
  float z1 = x1 + gumbel_at(g1a, g1b, (u32)i1);
  red[tid] = fmaxf(z0, z1); __syncthreads();
  for (int off = 128; off > 0; off >>= 1) {
    if (tid < off) red[tid] = fmaxf(red[tid], red[tid + off]);
    __syncthreads();
  }
  float m = red[0]; __syncthreads();
  float e0 = expf(z0 - m), e1 = expf(z1 - m);
  red[tid] = e0 + e1; __syncthreads();
  for (int off = 128; off > 0; off >>= 1) {
    if (tid < off) red[tid] += red[tid + off];
    __syncthreads();
  }
  float s = red[0]; __syncthreads();
  Y[i0] = e0 / s;
  Y[i1] = e1 / s;

  if (assignOut != nullptr) {
    float w0 = x0 + gumbel_at(g2a, g2b, (u32)i0);
    float w1 = x1 + gumbel_at(g2a, g2b, (u32)i1);
    red[tid] = fmaxf(w0, w1); __syncthreads();
    for (int off = 128; off > 0; off >>= 1) {
      if (tid < off) red[tid] = fmaxf(red[tid], red[tid + off]);
      __syncthreads();
    }
    float m2 = red[0]; __syncthreads();
    float f0 = expf(w0 - m2), f1 = expf(w1 - m2);
    red[tid] = f0 + f1; __syncthreads();
    for (int off = 128; off > 0; off >>= 1) {
      if (tid < off) red[tid] += red[tid + off];
      __syncthreads();
    }
    float s2 = red[0]; __syncthreads();
    float y0 = f0 / s2, y1v = f1 / s2;
    float bv; int bi;
    if (y1v > y0) { bv = y1v; bi = tid + 256; } else { bv = y0; bi = tid; }
    red[tid] = bv; redi[tid] = bi; __syncthreads();
    for (int off = 128; off > 0; off >>= 1) {
      if (tid < off) {
        float ov = red[tid + off]; int oi = redi[tid + off];
        if (ov > red[tid] || (ov == red[tid] && oi < redi[tid])) { red[tid] = ov; redi[tid] = oi; }
      }
      __syncthreads();
    }
    if (tid == 0) assignOut[b] = (float)redi[0];
  }
}

// ---------------- stochastic binary threshold ----------------
__global__ __launch_bounds__(256)
void k_binary(const float* __restrict__ knT, float* __restrict__ BIN, u32 k3a, u32 k3b) {
  int i = blockIdx.x * 256 + threadIdx.x;
  if (i >= KK * BB) return;
  int k = i / BB, b = i - k * BB;
  float x = knT[b * KK + k];
  float prob = (float)(1.0 / (1.0 + exp(-(double)x)));
  float eps = u01f(rbits32(k3a, k3b, (u32)i));
  BIN[i] = (prob > eps) ? 1.0f : 0.0f;
}

__global__ __launch_bounds__(256)
void k_rowsum(const float* __restrict__ BIN, float* __restrict__ rs) {
  __shared__ float sm[256];
  int k = blockIdx.x, tid = threadIdx.x;
  float s = 0.0f;
  for (int b = tid; b < BB; b += 256) s += BIN[k * BB + b];
  sm[tid] = s; __syncthreads();
  for (int off = 128; off > 0; off >>= 1) {
    if (tid < off) sm[tid] += sm[tid + off];
    __syncthreads();
  }
  if (tid == 0) rs[k] = sm[0];
}

__global__ __launch_bounds__(256)
void k_divrows(float* __restrict__ AGGK, const float* __restrict__ rs) {
  int i = blockIdx.x * 256 + threadIdx.x;
  int k = i >> 8;
  AGGK[i] = AGGK[i] / (rs[k] + 1e-8f);
}

__global__ __launch_bounds__(256)
void k_scale(float* __restrict__ x, const float* __restrict__ fac, int n) {
  int i = blockIdx.x * 256 + threadIdx.x;
  if (i < n) x[i] = x[i] * fac[0];
}

// ---------------- queue = 2*qk + 0.1*normal ----------------
__global__ __launch_bounds__(256)
void k_queue(const float* __restrict__ qk_in, const float* __restrict__ skp,
             float* __restrict__ QUEUE, u32 kqa, u32 kqb) {
  int i = blockIdx.x * 256 + threadIdx.x;
  if (i >= QQ * DD) return;
  float sk = skp[0];
  float qk = qk_in[i] * sk;
  float f = u01f(rbits32(kqa, kqb, (u32)i));
  const float lo = -0.99999994f;
  float u = fmaxf(lo, f * 2.0f + lo);
  float nv = 1.41421354f * erfinv32(u);
  float t = qk + 0.1f * nv;
  QUEUE[i] = t + qk;
}

__global__ __launch_bounds__(256)
void k_rowdot(const float* __restrict__ A, const float* __restrict__ Bv, float* __restrict__ outv) {
  __shared__ float sm[256];
  int r = blockIdx.x, tid = threadIdx.x;
  sm[tid] = A[r * 256 + tid] * Bv[r * 256 + tid];
  __syncthreads();
  for (int off = 128; off > 0; off >>= 1) {
    if (tid < off) sm[tid] += sm[tid + off];
    __syncthreads();
  }
  if (tid == 0) outv[r] = sm[0];
}

// ---------------- f32 -> bf16 conversion (4 elems/thread) ----------------
__global__ __launch_bounds__(256)
void k_cvt_bf16(const float* __restrict__ src, unsigned short* __restrict__ dst, int n) {
  int i = (blockIdx.x * 256 + threadIdx.x) * 4;
  if (i >= n) return;
  float4 v = *(const float4*)(src + i);
  ushort2 a, b;
  a.x = f2bf(v.x); a.y = f2bf(v.y);
  b.x = f2bf(v.z); b.y = f2bf(v.w);
  *(ushort2*)(dst + i) = a;
  *(ushort2*)(dst + i + 2) = b;
}

// ---------------- fused bf16-MFMA GEMM + online logsumexp ----------------
// grid (M/64, nsplit), block 256 = 4 waves; wave w owns rows [bx*64+w*16, +16),
// sweeps its y-slice of Lper columns. A fragments live in registers for the
// whole sweep; B fragments are contiguous 16B loads straight from global.
__global__ __launch_bounds__(256)
void k_lse_mfma(const unsigned short* __restrict__ Qb, const unsigned short* __restrict__ Nb,
                const float* __restrict__ scale_ptr, int Lper, int nsplit,
                float* __restrict__ pm, float* __restrict__ ps) {
  int tid = threadIdx.x;
  int wave = tid >> 6, lane = tid & 63;
  int rowBase = blockIdx.x * 64 + wave * 16;
  int j0 = blockIdx.y * Lper;
  float lsc = scale_ptr[0] / 0.07f;
  int lr = lane & 15;          // A row / B col within 16-tile
  int lk = (lane >> 4) * 8;    // k sub-offset (8 contiguous bf16 = 16 B)

  short8 afr[8];
#pragma unroll
  for (int kf = 0; kf < 8; kf++)
    afr[kf] = *(const short8*)(Qb + (size_t)(rowBase + lr) * 256 + kf * 32 + lk);

  float m[4], s[4];
#pragma unroll
  for (int r = 0; r < 4; r++) { m[r] = -1e30f; s[r] = 0.0f; }

  for (int jc = 0; jc < Lper; jc += 64) {
#pragma unroll
    for (int jt = 0; jt < 4; jt++) {
      const unsigned short* bbase = Nb + (size_t)(j0 + jc + jt * 16 + lr) * 256 + lk;
      f32x4 acc = {0.f, 0.f, 0.f, 0.f};
#pragma unroll
      for (int kf = 0; kf < 8; kf++) {
        short8 bfr = *(const short8*)(bbase + kf * 32);
        acc = __builtin_amdgcn_mfma_f32_16x16x32_bf16(afr[kf], bfr, acc, 0, 0, 0);
      }
      // C layout: col = lane&15, row = (lane>>4)*4 + r  [m89]
#pragma unroll
      for (int r = 0; r < 4; r++) {
        float z = acc[r] * lsc;
        float d = z - m[r];
        float e = expf(-fabsf(d));   // exp(-1e30) -> 0, no NaN on first touch
        if (d > 0.0f) { s[r] = fmaf(s[r], e, 1.0f); m[r] = z; }
        else s[r] += e;
      }
    }
  }
  // merge across the 16 lanes holding the same rows (same lane>>4 group)
#pragma unroll
  for (int off = 1; off < 16; off <<= 1) {
#pragma unroll
    for (int r = 0; r < 4; r++) {
      float m2 = __shfl_xor(m[r], off, 64);
      float s2 = __shfl_xor(s[r], off, 64);
      float mn = fmaxf(m[r], m2);
      s[r] = s[r] * expf(m[r] - mn) + s2 * expf(m2 - mn);
      m[r] = mn;
    }
  }
  if (lr == 0) {
    int rg = (lane >> 4) * 4;
#pragma unroll
    for (int r = 0; r < 4; r++) {
      int row = rowBase + rg + r;
      pm[(size_t)row * nsplit + blockIdx.y] = m[r];
      ps[(size_t)row * nsplit + blockIdx.y] = s[r];
    }
  }
}

__global__ __launch_bounds__(256)
void k_lse_final(const float* __restrict__ pm, const float* __restrict__ ps, int nsplit,
                 const float* __restrict__ lpos, int M, float* __restrict__ outSlot) {
  __shared__ float sm[256];
  int tid = threadIdx.x;
  float acc = 0.0f;
  for (int row = tid; row < M; row += 256) {
    float m = -1e30f, s = 0.0f;
    for (int t = 0; t < nsplit; t++) {
      float m2 = pm[row * nsplit + t], s2 = ps[row * nsplit + t];
      float mn = fmaxf(m, m2);
      s = s * expf(m - mn) + s2 * expf(m2 - mn);
      m = mn;
    }
    float z0 = lpos[row] / 0.07f;
    float mn = fmaxf(m, z0);
    s = s * expf(m - mn) + expf(z0 - mn);
    m = mn;
    float lse = logf(s) + m;
    acc += (lse - z0);
  }
  sm[tid] = acc; __syncthreads();
  for (int off = 128; off > 0; off >>= 1) {
    if (tid < off) sm[tid] += sm[tid + off];
    __syncthreads();
  }
  if (tid == 0) outSlot[0] = sm[0] / (float)M;
}

__global__ void k_loss_add(const float* __restrict__ slots, float* __restrict__ outv) {
  outv[0] = slots[0] + slots[1];
}

// ---------------- launch ----------------
extern "C" void kernel_launch(void* const* d_in, const int* in_sizes, int n_in,
                              void* d_out, int out_size, void* d_ws, size_t ws_size,
                              hipStream_t stream) {
  const float* feat[2] = {(const float*)d_in[0], (const float*)d_in[1]};
  const float* ctx[2]  = {(const float*)d_in[2], (const float*)d_in[3]};
  const float* queue_n = (const float*)d_in[4];
  const float* queue_k = (const float*)d_in[5];

  float* W = (float*)d_ws;
  size_t o = 0;
  float* T     = W + o; o += (size_t)BB * KK;
  float* Yb    = W + o; o += (size_t)BB * KK;
  float* BIN   = W + o; o += (size_t)KK * BB;
  float* AGGN1 = W + o; o += (size_t)BB * DD;
  float* AGGK1 = W + o; o += (size_t)KK * DD;
  float* QUEUE = W + o; o += (size_t)QQ * DD;
  float* RS    = W + o; o += KK;
  float* PART  = W + o; o += 256;
  float* SCAL  = W + o; o += 8;
  float* PM    = W + o; o += (size_t)BB * 16;
  float* PS    = W + o; o += (size_t)BB * 16;
  float* LPOSN = W + o; o += BB;
  float* LPOSK = W + o; o += KK;
  float* LOSS  = W + o; o += 2;

  // bf16 loss operands overlay the dead T/Yb/BIN region (25.2 MB >= 23.3 MB)
  unsigned short* QNb  = (unsigned short*)T;                 // 32768*256
  unsigned short* QUb  = QNb + (size_t)LL * DD;              // 8192*256
  unsigned short* AGNb = QUb + (size_t)QQ * DD;              // 4096*256
  unsigned short* AGKb = AGNb + (size_t)BB * DD;             // 512*256

  float* out = (float*)d_out;
  float* outAssign = out;
  float* outAggn2  = out + BB;
  float* outAggk2  = out + BB + (size_t)BB * DD;
  float* outLoss   = out + BB + (size_t)BB * DD + (size_t)KK * DD;

  u32 kq0, kq1, kc[2][2];
  tf2x32(0u, 42u, 0u, 0u, kq0, kq1);
  tf2x32(0u, 42u, 0u, 1u, kc[0][0], kc[0][1]);
  tf2x32(0u, 42u, 0u, 2u, kc[1][0], kc[1][1]);
  u32 sub[2][3][2];
  for (int br = 0; br < 2; br++)
    for (int t = 0; t < 3; t++)
      tf2x32(kc[br][0], kc[br][1], 0u, (u32)t, sub[br][t][0], sub[br][t][1]);

  dim3 thr16(16, 16);

  k_sumsq<<<256, 256, 0, stream>>>(queue_n, LL * DD, PART);
  k_finalize_rsqrt<<<1, 256, 0, stream>>>(PART, SCAL + 0);   // sn
  k_sumsq<<<256, 256, 0, stream>>>(queue_k, QQ * DD, PART);
  k_finalize_rsqrt<<<1, 256, 0, stream>>>(PART, SCAL + 1);   // sk

  for (int br = 0; br < 2; br++) {
    float* aggn = (br == 0) ? AGGN1 : outAggn2;
    float* aggk = (br == 0) ? AGGK1 : outAggk2;
    k_gemm_nt<<<dim3(KK / 16, BB / 16), thr16, 0, stream>>>(feat[br], ctx[br], T, BB, KK);
    k_softmax_assign<<<BB, 256, 0, stream>>>(T, Yb, br == 0 ? outAssign : nullptr,
        sub[br][0][0], sub[br][0][1], sub[br][1][0], sub[br][1][1]);
    k_binary<<<(KK * BB) / 256, 256, 0, stream>>>(T, BIN, sub[br][2][0], sub[br][2][1]);
    k_rowsum<<<KK, 256, 0, stream>>>(BIN, RS);
    k_gemm_nn<<<dim3(DD / 16, BB / 16), thr16, 0, stream>>>(Yb, ctx[br], aggn, BB, DD, KK);
    k_gemm_nn<<<dim3(DD / 16, KK / 16), thr16, 0, stream>>>(BIN, feat[br], aggk, KK, DD, BB);
    k_divrows<<<(KK * DD) / 256, 256, 0, stream>>>(aggk, RS);
    k_sumsq<<<256, 256, 0, stream>>>(aggn, BB * DD, PART);
    k_finalize_rsqrt<<<1, 256, 0, stream>>>(PART, SCAL + 3);
    k_scale<<<(BB * DD) / 256, 256, 0, stream>>>(aggn, SCAL + 3, BB * DD);
    k_sumsq<<<256, 256, 0, stream>>>(aggk, KK * DD, PART);
    k_finalize_rsqrt<<<1, 256, 0, stream>>>(PART, SCAL + 4);
    k_scale<<<(KK * DD) / 256, 256, 0, stream>>>(aggk, SCAL + 4, KK * DD);
  }

  k_queue<<<(QQ * DD) / 256, 256, 0, stream>>>(queue_k, SCAL + 1, QUEUE, kq0, kq1);
  k_sumsq<<<256, 256, 0, stream>>>(QUEUE, QQ * DD, PART);
  k_finalize_rsqrt<<<1, 256, 0, stream>>>(PART, SCAL + 2);   // fq

  // positives (f32, unchanged)
  k_rowdot<<<BB, 256, 0, stream>>>(AGGN1, outAggn2, LPOSN);
  k_rowdot<<<KK, 256, 0, stream>>>(AGGK1, outAggk2, LPOSK);

  // bf16 conversions (T/Yb/BIN are dead past this point)
  k_cvt_bf16<<<(LL * DD) / 1024, 256, 0, stream>>>(queue_n, QNb, LL * DD);
  k_cvt_bf16<<<(QQ * DD) / 1024, 256, 0, stream>>>(QUEUE, QUb, QQ * DD);
  k_cvt_bf16<<<(BB * DD) / 1024, 256, 0, stream>>>(AGGN1, AGNb, BB * DD);
  k_cvt_bf16<<<(KK * DD) / 1024, 256, 0, stream>>>(AGGK1, AGKb, KK * DD);

  // loss_n: q = agg_n_1, negs = queue_n (scale sn folded into logits)
  k_lse_mfma<<<dim3(BB / 64, 16), 256, 0, stream>>>(AGNb, QNb, SCAL + 0, LL / 16, 16, PM, PS);
  k_lse_final<<<1, 256, 0, stream>>>(PM, PS, 16, LPOSN, BB, LOSS + 0);
  // loss_k: q = agg_k_1, negs = QUEUE (scale fq folded into logits)
  k_lse_mfma<<<dim3(KK / 64, 32), 256, 0, stream>>>(AGKb, QUb, SCAL + 2, QQ / 32, 32, PM, PS);
  k_lse_final<<<1, 256, 0, stream>>>(PM, PS, 32, LPOSK, KK, LOSS + 1);
  k_loss_add<<<1, 1, 0, stream>>>(LOSS, outLoss);
}

// Round 3
// 639.221 us; speedup vs baseline: 3.1144x; 2.0821x over previous
//
#include <hip/hip_runtime.h>
#include <stdint.h>
#include <math.h>

typedef unsigned int u32;
typedef __attribute__((ext_vector_type(8))) short short8;
typedef __attribute__((ext_vector_type(4))) float f32x4;

#define BB 4096
#define DD 256
#define KK 512
#define LL 32768
#define QQ 8192

// ---------------- Threefry2x32 (JAX-exact, 20 rounds) ----------------
__host__ __device__ inline void tf2x32(u32 k0, u32 k1, u32 c0, u32 c1, u32& o0, u32& o1) {
  u32 ks2 = k0 ^ k1 ^ 0x1BD11BDAu;
  u32 x0 = c0 + k0, x1 = c1 + k1;
#define TF_R(r) { x0 += x1; x1 = ((x1 << (r)) | (x1 >> (32 - (r)))); x1 ^= x0; }
  TF_R(13) TF_R(15) TF_R(26) TF_R(6)
  x0 += k1; x1 += ks2 + 1u;
  TF_R(17) TF_R(29) TF_R(16) TF_R(24)
  x0 += ks2; x1 += k0 + 2u;
  TF_R(13) TF_R(15) TF_R(26) TF_R(6)
  x0 += k0; x1 += k1 + 3u;
  TF_R(17) TF_R(29) TF_R(16) TF_R(24)
  x0 += k1; x1 += ks2 + 4u;
  TF_R(13) TF_R(15) TF_R(26) TF_R(6)
  x0 += ks2; x1 += k0 + 5u;
#undef TF_R
  o0 = x0; o1 = x1;
}

__device__ inline u32 rbits32(u32 k0, u32 k1, u32 i) {
  u32 a, b;
  tf2x32(k0, k1, 0u, i, a, b);
  return a ^ b;
}

__device__ inline float u01f(u32 bits) {
  return __uint_as_float(0x3f800000u | (bits >> 9)) - 1.0f;
}

__device__ inline float gumbel_at(u32 k0, u32 k1, u32 i) {
  float f = u01f(rbits32(k0, k1, i));
  float u = fmaxf(1e-20f, f + 1e-20f);
  float l1 = (float)log((double)u);
  float l2 = (float)log((double)(-l1));
  return -l2;
}

// XLA f32 ErfInv (Giles polynomial)
__device__ inline float erfinv32(float x) {
  float w = -log1pf(-x * x);
  float p;
  if (w < 5.0f) {
    w -= 2.5f;
    p = 2.81022636e-08f;
    p = fmaf(p, w, 3.43273939e-07f);
    p = fmaf(p, w, -3.5233877e-06f);
    p = fmaf(p, w, -4.39150654e-06f);
    p = fmaf(p, w, 0.00021858087f);
    p = fmaf(p, w, -0.00125372503f);
    p = fmaf(p, w, -0.00417768164f);
    p = fmaf(p, w, 0.246640727f);
    p = fmaf(p, w, 1.50140941f);
  } else {
    w = sqrtf(w) - 3.0f;
    p = -0.000200214257f;
    p = fmaf(p, w, 0.000100950558f);
    p = fmaf(p, w, 0.00134934322f);
    p = fmaf(p, w, -0.00367342844f);
    p = fmaf(p, w, 0.00573950773f);
    p = fmaf(p, w, -0.0076224613f);
    p = fmaf(p, w, 0.00943887047f);
    p = fmaf(p, w, 1.00167406f);
    p = fmaf(p, w, 2.83297682f);
  }
  return p * x;
}

__device__ inline unsigned short f2bf(float f) {
  u32 u = __float_as_uint(f);
  u32 r = (u + 0x7FFFu + ((u >> 16) & 1u)) >> 16;
  return (unsigned short)r;
}

// ---------------- Reductions ----------------
__global__ __launch_bounds__(256)
void k_sumsq(const float* __restrict__ x, int n, float* __restrict__ partial) {
  __shared__ float sm[256];
  float s = 0.0f;
  for (int i = blockIdx.x * 256 + threadIdx.x; i < n; i += gridDim.x * 256) {
    float v = x[i]; s = fmaf(v, v, s);
  }
  sm[threadIdx.x] = s; __syncthreads();
  for (int off = 128; off > 0; off >>= 1) {
    if (threadIdx.x < off) sm[threadIdx.x] += sm[threadIdx.x + off];
    __syncthreads();
  }
  if (threadIdx.x == 0) partial[blockIdx.x] = sm[0];
}

__global__ __launch_bounds__(256)
void k_finalize_rsqrt(const float* __restrict__ partial, float* __restrict__ outv) {
  __shared__ float sm[256];
  int tid = threadIdx.x;
  sm[tid] = partial[tid];
  __syncthreads();
  for (int off = 128; off > 0; off >>= 1) {
    if (tid < off) sm[tid] += sm[tid + off];
    __syncthreads();
  }
  if (tid == 0) {
    float ssum = fmaxf(sm[0], 1e-12f);
    outv[0] = (float)(1.0 / sqrt((double)ssum));
  }
}

// ---------------- f32 GEMMs: 64x64 tile, 4x4 register tile ----------------
// C[M x N] = A[M x 256] * Bm[N x 256]^T ; grid (N/64, M/64)
__global__ __launch_bounds__(256)
void k_gemm_nt64(const float* __restrict__ A, const float* __restrict__ Bm,
                 float* __restrict__ C, int N) {
  __shared__ float As[16][68], Bs[16][68];
  int tid = threadIdx.x;
  int tx = tid & 15, ty = tid >> 4;
  int rowBase = blockIdx.y * 64, colBase = blockIdx.x * 64;
  float c[4][4] = {};
  for (int kt = 0; kt < 256; kt += 16) {
#pragma unroll
    for (int q = 0; q < 4; q++) {
      int idx = tid + 256 * q;
      int kkx = idx & 15, rr = idx >> 4;
      As[kkx][rr] = A[(size_t)(rowBase + rr) * 256 + kt + kkx];
      Bs[kkx][rr] = Bm[(size_t)(colBase + rr) * 256 + kt + kkx];
    }
    __syncthreads();
#pragma unroll
    for (int kx = 0; kx < 16; kx++) {
      float4 a4 = *(const float4*)&As[kx][ty * 4];
      float4 b4 = *(const float4*)&Bs[kx][tx * 4];
      float av[4] = {a4.x, a4.y, a4.z, a4.w};
      float bv[4] = {b4.x, b4.y, b4.z, b4.w};
#pragma unroll
      for (int r = 0; r < 4; r++)
#pragma unroll
        for (int q = 0; q < 4; q++)
          c[r][q] = fmaf(av[r], bv[q], c[r][q]);
    }
    __syncthreads();
  }
#pragma unroll
  for (int r = 0; r < 4; r++)
#pragma unroll
    for (int q = 0; q < 4; q++)
      C[(size_t)(rowBase + ty * 4 + r) * N + colBase + tx * 4 + q] = c[r][q];
}

// C[M x N] = A[M x K] * Bm[K x N]; grid (N/64, M/64, S); z covers K rows [z*Kc,(z+1)*Kc)
// If S>1, C is a partials buffer [S][M][N].
__global__ __launch_bounds__(256)
void k_gemm_nn64(const float* __restrict__ A, const float* __restrict__ Bm,
                 float* __restrict__ C, int N, int K, int M, int Kc) {
  __shared__ float As[16][68], Bs[16][68];
  int tid = threadIdx.x;
  int tx = tid & 15, ty = tid >> 4;
  int rowBase = blockIdx.y * 64, colBase = blockIdx.x * 64;
  int k0 = blockIdx.z * Kc;
  float c[4][4] = {};
  for (int kt = k0; kt < k0 + Kc; kt += 16) {
#pragma unroll
    for (int q = 0; q < 4; q++) {
      int idx = tid + 256 * q;
      int kkx = idx & 15, rr = idx >> 4;
      As[kkx][rr] = A[(size_t)(rowBase + rr) * K + kt + kkx];
      int kk = (tid >> 6) * 4 + q;
      int jj = tid & 63;
      Bs[kk][jj] = Bm[(size_t)(kt + kk) * N + colBase + jj];
    }
    __syncthreads();
#pragma unroll
    for (int kx = 0; kx < 16; kx++) {
      float4 a4 = *(const float4*)&As[kx][ty * 4];
      float4 b4 = *(const float4*)&Bs[kx][tx * 4];
      float av[4] = {a4.x, a4.y, a4.z, a4.w};
      float bv[4] = {b4.x, b4.y, b4.z, b4.w};
#pragma unroll
      for (int r = 0; r < 4; r++)
#pragma unroll
        for (int q = 0; q < 4; q++)
          c[r][q] = fmaf(av[r], bv[q], c[r][q]);
    }
    __syncthreads();
  }
  float* dst = C + (size_t)blockIdx.z * M * N;
#pragma unroll
  for (int r = 0; r < 4; r++)
#pragma unroll
    for (int q = 0; q < 4; q++)
      dst[(size_t)(rowBase + ty * 4 + r) * N + colBase + tx * 4 + q] = c[r][q];
}

// sum split-K partials and divide by row-sum (N fixed = 256)
__global__ __launch_bounds__(256)
void k_reduce_div(const float* __restrict__ Cp, int S, int MN,
                  const float* __restrict__ rs, float* __restrict__ out) {
  int i = blockIdx.x * 256 + threadIdx.x;
  if (i >= MN) return;
  float s = 0.0f;
  for (int t = 0; t < S; t++) s += Cp[(size_t)t * MN + i];
  out[i] = s / (rs[i >> 8] + 1e-8f);
}

// ---------------- softmax(y1) + hard argmax(y2) per row ----------------
__global__ __launch_bounds__(256)
void k_softmax_assign(const float* __restrict__ knT, float* __restrict__ Y,
                      float* __restrict__ assignOut,
                      u32 g1a, u32 g1b, u32 g2a, u32 g2b) {
  __shared__ float red[256];
  __shared__ int redi[256];
  int b = blockIdx.x, tid = threadIdx.x;
  int i0 = b * KK + tid, i1 = i0 + 256;
  float x0 = knT[i0], x1 = knT[i1];

  float z0 = x0 + gumbel_at(g1a, g1b, (u32)i0);
  float z1 = x1 + gumbel_at(g1a, g1b, (u32)i1);
  red[tid] = fmaxf(z0, z1); __syncthreads();
  for (int off = 128; off > 0; off >>= 1) {
    if (tid < off) red[tid] = fmaxf(red[tid], red[tid + off]);
    __syncthreads();
  }
  float m = red[0]; __syncthreads();
  float e0 = expf(z0 - m), e1 = expf(z1 - m);
  red[tid] = e0 + e1; __syncthreads();
  for (int off = 128; off > 0; off >>= 1) {
    if (tid < off) red[tid] += red[tid + off];
    __syncthreads();
  }
  float s = red[0]; __syncthreads();
  Y[i0] = e0 / s;
  Y[i1] = e1 / s;

  if (assignOut != nullptr) {
    float w0 = x0 + gumbel_at(g2a, g2b, (u32)i0);
    float w1 = x1 + gumbel_at(g2a, g2b, (u32)i1);
    red[tid] = fmaxf(w0, w1); __syncthreads();
    for (int off = 128; off > 0; off >>= 1) {
      if (tid < off) red[tid] = fmaxf(red[tid], red[tid + off]);
      __syncthreads();
    }
    float m2 = red[0]; __syncthreads();
    float f0 = expf(w0 - m2), f1 = expf(w1 - m2);
    red[tid] = f0 + f1; __syncthreads();
    for (int off = 128; off > 0; off >>= 1) {
      if (tid < off) red[tid] += red[tid + off];
      __syncthreads();
    }
    float s2 = red[0]; __syncthreads();
    float y0 = f0 / s2, y1v = f1 / s2;
    float bv; int bi;
    if (y1v > y0) { bv = y1v; bi = tid + 256; } else { bv = y0; bi = tid; }
    red[tid] = bv; redi[tid] = bi; __syncthreads();
    for (int off = 128; off > 0; off >>= 1) {
      if (tid < off) {
        float ov = red[tid + off]; int oi = redi[tid + off];
        if (ov > red[tid] || (ov == red[tid] && oi < redi[tid])) { red[tid] = ov; redi[tid] = oi; }
      }
      __syncthreads();
    }
    if (tid == 0) assignOut[b] = (float)redi[0];
  }
}

// ---------------- stochastic binary threshold ----------------
__global__ __launch_bounds__(256)
void k_binary(const float* __restrict__ knT, float* __restrict__ BIN, u32 k3a, u32 k3b) {
  int i = blockIdx.x * 256 + threadIdx.x;
  if (i >= KK * BB) return;
  int k = i / BB, b = i - k * BB;
  float x = knT[b * KK + k];
  float prob = (float)(1.0 / (1.0 + exp(-(double)x)));
  float eps = u01f(rbits32(k3a, k3b, (u32)i));
  BIN[i] = (prob > eps) ? 1.0f : 0.0f;
}

__global__ __launch_bounds__(256)
void k_rowsum(const float* __restrict__ BIN, float* __restrict__ rs) {
  __shared__ float sm[256];
  int k = blockIdx.x, tid = threadIdx.x;
  float s = 0.0f;
  for (int b = tid; b < BB; b += 256) s += BIN[k * BB + b];
  sm[tid] = s; __syncthreads();
  for (int off = 128; off > 0; off >>= 1) {
    if (tid < off) sm[tid] += sm[tid + off];
    __syncthreads();
  }
  if (tid == 0) rs[k] = sm[0];
}

__global__ __launch_bounds__(256)
void k_scale(float* __restrict__ x, const float* __restrict__ fac, int n) {
  int i = blockIdx.x * 256 + threadIdx.x;
  if (i < n) x[i] = x[i] * fac[0];
}

// ---------------- queue = 2*qk + 0.1*normal ----------------
__global__ __launch_bounds__(256)
void k_queue(const float* __restrict__ qk_in, const float* __restrict__ skp,
             float* __restrict__ QUEUE, u32 kqa, u32 kqb) {
  int i = blockIdx.x * 256 + threadIdx.x;
  if (i >= QQ * DD) return;
  float sk = skp[0];
  float qk = qk_in[i] * sk;
  float f = u01f(rbits32(kqa, kqb, (u32)i));
  const float lo = -0.99999994f;
  float u = fmaxf(lo, f * 2.0f + lo);
  float nv = 1.41421354f * erfinv32(u);
  float t = qk + 0.1f * nv;
  QUEUE[i] = t + qk;
}

__global__ __launch_bounds__(256)
void k_rowdot(const float* __restrict__ A, const float* __restrict__ Bv, float* __restrict__ outv) {
  __shared__ float sm[256];
  int r = blockIdx.x, tid = threadIdx.x;
  sm[tid] = A[r * 256 + tid] * Bv[r * 256 + tid];
  __syncthreads();
  for (int off = 128; off > 0; off >>= 1) {
    if (tid < off) sm[tid] += sm[tid + off];
    __syncthreads();
  }
  if (tid == 0) outv[r] = sm[0];
}

// ---------------- f32 -> bf16 conversion (4 elems/thread) ----------------
__global__ __launch_bounds__(256)
void k_cvt_bf16(const float* __restrict__ src, unsigned short* __restrict__ dst, int n) {
  int i = (blockIdx.x * 256 + threadIdx.x) * 4;
  if (i >= n) return;
  float4 v = *(const float4*)(src + i);
  ushort2 a, b;
  a.x = f2bf(v.x); a.y = f2bf(v.y);
  b.x = f2bf(v.z); b.y = f2bf(v.w);
  *(ushort2*)(dst + i) = a;
  *(ushort2*)(dst + i + 2) = b;
}

// ---------------- fused bf16-MFMA GEMM + sum-exp (fixed m=0) ----------------
// Valid because |logits| < 0.01 (globally-l2-normalized operands).
// grid (M/256, nsplit), block 256 = 4 waves; wave owns 64 rows via 4 A-tilesets.
__global__ __launch_bounds__(256)
void k_lse_mfma2(const unsigned short* __restrict__ Qb, const unsigned short* __restrict__ Nb,
                 const float* __restrict__ scale_ptr, int Lper, int nsplit,
                 float* __restrict__ ps) {
  int tid = threadIdx.x;
  int wave = tid >> 6, lane = tid & 63;
  int rowBase = blockIdx.x * 256 + wave * 64;
  int j0 = blockIdx.y * Lper;
  float lsc = scale_ptr[0] / 0.07f;
  int lr = lane & 15;
  int lk = (lane >> 4) * 8;

  short8 afr[4][8];
#pragma unroll
  for (int ts = 0; ts < 4; ts++)
#pragma unroll
    for (int kf = 0; kf < 8; kf++)
      afr[ts][kf] = *(const short8*)(Qb + (size_t)(rowBase + ts * 16 + lr) * 256 + kf * 32 + lk);

  float s[4][4];
#pragma unroll
  for (int ts = 0; ts < 4; ts++)
#pragma unroll
    for (int r = 0; r < 4; r++) s[ts][r] = 0.0f;

  for (int j = 0; j < Lper; j += 16) {
    const unsigned short* bbase = Nb + (size_t)(j0 + j + lr) * 256 + lk;
    short8 bfr[8];
#pragma unroll
    for (int kf = 0; kf < 8; kf++) bfr[kf] = *(const short8*)(bbase + kf * 32);
#pragma unroll
    for (int ts = 0; ts < 4; ts++) {
      f32x4 acc = {0.f, 0.f, 0.f, 0.f};
#pragma unroll
      for (int kf = 0; kf < 8; kf++)
        acc = __builtin_amdgcn_mfma_f32_16x16x32_bf16(afr[ts][kf], bfr[kf], acc, 0, 0, 0);
#pragma unroll
      for (int r = 0; r < 4; r++)
        s[ts][r] += __expf(acc[r] * lsc);
    }
  }
#pragma unroll
  for (int off = 1; off < 16; off <<= 1)
#pragma unroll
    for (int ts = 0; ts < 4; ts++)
#pragma unroll
      for (int r = 0; r < 4; r++)
        s[ts][r] += __shfl_xor(s[ts][r], off, 64);
  if (lr == 0) {
    int rg = (lane >> 4) * 4;
#pragma unroll
    for (int ts = 0; ts < 4; ts++)
#pragma unroll
      for (int r = 0; r < 4; r++)
        ps[(size_t)(rowBase + ts * 16 + rg + r) * nsplit + blockIdx.y] = s[ts][r];
  }
}

__global__ __launch_bounds__(256)
void k_lse_final2(const float* __restrict__ ps, int nsplit,
                  const float* __restrict__ lpos, int M, float* __restrict__ outSlot) {
  __shared__ float sm[256];
  int tid = threadIdx.x;
  float acc = 0.0f;
  for (int row = tid; row < M; row += 256) {
    float s = 0.0f;
    for (int t = 0; t < nsplit; t++) s += ps[(size_t)row * nsplit + t];
    float z0 = lpos[row] / 0.07f;
    s += expf(z0);
    acc += logf(s) - z0;
  }
  sm[tid] = acc; __syncthreads();
  for (int off = 128; off > 0; off >>= 1) {
    if (tid < off) sm[tid] += sm[tid + off];
    __syncthreads();
  }
  if (tid == 0) outSlot[0] = sm[0] / (float)M;
}

__global__ void k_loss_add(const float* __restrict__ slots, float* __restrict__ outv) {
  outv[0] = slots[0] + slots[1];
}

// ---------------- launch ----------------
extern "C" void kernel_launch(void* const* d_in, const int* in_sizes, int n_in,
                              void* d_out, int out_size, void* d_ws, size_t ws_size,
                              hipStream_t stream) {
  const float* feat[2] = {(const float*)d_in[0], (const float*)d_in[1]};
  const float* ctx[2]  = {(const float*)d_in[2], (const float*)d_in[3]};
  const float* queue_n = (const float*)d_in[4];
  const float* queue_k = (const float*)d_in[5];

  float* W = (float*)d_ws;
  size_t o = 0;
  float* T     = W + o; o += (size_t)BB * KK;
  float* Yb    = W + o; o += (size_t)BB * KK;   // also reused as split-K partials (CP)
  float* BIN   = W + o; o += (size_t)KK * BB;
  float* AGGN1 = W + o; o += (size_t)BB * DD;
  float* AGGK1 = W + o; o += (size_t)KK * DD;
  float* QUEUE = W + o; o += (size_t)QQ * DD;
  float* RS    = W + o; o += KK;
  float* PART  = W + o; o += 256;
  float* SCAL  = W + o; o += 8;
  float* PSBUF = W + o; o += (size_t)BB * 32;   // 131072 floats (PM+PS merged)
  float* LPOSN = W + o; o += BB;
  float* LPOSK = W + o; o += KK;
  float* LOSS  = W + o; o += 2;

  // bf16 loss operands overlay the dead T/Yb/BIN region (written after branch loop)
  unsigned short* QNb  = (unsigned short*)T;                 // 32768*256
  unsigned short* QUb  = QNb + (size_t)LL * DD;              // 8192*256
  unsigned short* AGNb = QUb + (size_t)QQ * DD;              // 4096*256
  unsigned short* AGKb = AGNb + (size_t)BB * DD;             // 512*256
  float* CP = Yb;                                            // split-K partials (8*512*256)

  float* out = (float*)d_out;
  float* outAssign = out;
  float* outAggn2  = out + BB;
  float* outAggk2  = out + BB + (size_t)BB * DD;
  float* outLoss   = out + BB + (size_t)BB * DD + (size_t)KK * DD;

  u32 kq0, kq1, kc[2][2];
  tf2x32(0u, 42u, 0u, 0u, kq0, kq1);
  tf2x32(0u, 42u, 0u, 1u, kc[0][0], kc[0][1]);
  tf2x32(0u, 42u, 0u, 2u, kc[1][0], kc[1][1]);
  u32 sub[2][3][2];
  for (int br = 0; br < 2; br++)
    for (int t = 0; t < 3; t++)
      tf2x32(kc[br][0], kc[br][1], 0u, (u32)t, sub[br][t][0], sub[br][t][1]);

  k_sumsq<<<256, 256, 0, stream>>>(queue_n, LL * DD, PART);
  k_finalize_rsqrt<<<1, 256, 0, stream>>>(PART, SCAL + 0);   // sn
  k_sumsq<<<256, 256, 0, stream>>>(queue_k, QQ * DD, PART);
  k_finalize_rsqrt<<<1, 256, 0, stream>>>(PART, SCAL + 1);   // sk

  for (int br = 0; br < 2; br++) {
    float* aggn = (br == 0) ? AGGN1 : outAggn2;
    float* aggk = (br == 0) ? AGGK1 : outAggk2;
    // knT[b,k] = dot(feat_b, ctx_k)  (f32-exact path for discrete consumers)
    k_gemm_nt64<<<dim3(KK / 64, BB / 64), 256, 0, stream>>>(feat[br], ctx[br], T, KK);
    k_softmax_assign<<<BB, 256, 0, stream>>>(T, Yb, br == 0 ? outAssign : nullptr,
        sub[br][0][0], sub[br][0][1], sub[br][1][0], sub[br][1][1]);
    k_binary<<<(KK * BB) / 256, 256, 0, stream>>>(T, BIN, sub[br][2][0], sub[br][2][1]);
    k_rowsum<<<KK, 256, 0, stream>>>(BIN, RS);
    // agg_n = Y @ ctx   (direct, S=1)
    k_gemm_nn64<<<dim3(DD / 64, BB / 64, 1), 256, 0, stream>>>(Yb, ctx[br], aggn, DD, KK, BB, KK);
    // agg_k = BIN @ feat (split-K S=8, partials in CP=Yb region; Yb dead after agg_n)
    k_gemm_nn64<<<dim3(DD / 64, KK / 64, 8), 256, 0, stream>>>(BIN, feat[br], CP, DD, BB, KK, 512);
    k_reduce_div<<<(KK * DD) / 256, 256, 0, stream>>>(CP, 8, KK * DD, RS, aggk);
    k_sumsq<<<256, 256, 0, stream>>>(aggn, BB * DD, PART);
    k_finalize_rsqrt<<<1, 256, 0, stream>>>(PART, SCAL + 3);
    k_scale<<<(BB * DD) / 256, 256, 0, stream>>>(aggn, SCAL + 3, BB * DD);
    k_sumsq<<<256, 256, 0, stream>>>(aggk, KK * DD, PART);
    k_finalize_rsqrt<<<1, 256, 0, stream>>>(PART, SCAL + 4);
    k_scale<<<(KK * DD) / 256, 256, 0, stream>>>(aggk, SCAL + 4, KK * DD);
  }

  k_queue<<<(QQ * DD) / 256, 256, 0, stream>>>(queue_k, SCAL + 1, QUEUE, kq0, kq1);
  k_sumsq<<<256, 256, 0, stream>>>(QUEUE, QQ * DD, PART);
  k_finalize_rsqrt<<<1, 256, 0, stream>>>(PART, SCAL + 2);   // fq

  // positives (f32)
  k_rowdot<<<BB, 256, 0, stream>>>(AGGN1, outAggn2, LPOSN);
  k_rowdot<<<KK, 256, 0, stream>>>(AGGK1, outAggk2, LPOSK);

  // bf16 conversions (T/Yb/BIN dead from here)
  k_cvt_bf16<<<(LL * DD) / 1024, 256, 0, stream>>>(queue_n, QNb, LL * DD);
  k_cvt_bf16<<<(QQ * DD) / 1024, 256, 0, stream>>>(QUEUE, QUb, QQ * DD);
  k_cvt_bf16<<<(BB * DD) / 1024, 256, 0, stream>>>(AGGN1, AGNb, BB * DD);
  k_cvt_bf16<<<(KK * DD) / 1024, 256, 0, stream>>>(AGGK1, AGKb, KK * DD);

  // loss_n: q = agg_n_1, negs = queue_n (sn folded into logit scale)
  k_lse_mfma2<<<dim3(BB / 256, 32), 256, 0, stream>>>(AGNb, QNb, SCAL + 0, LL / 32, 32, PSBUF);
  k_lse_final2<<<1, 256, 0, stream>>>(PSBUF, 32, LPOSN, BB, LOSS + 0);
  // loss_k: q = agg_k_1, negs = QUEUE (fq folded into logit scale)
  k_lse_mfma2<<<dim3(KK / 256, 128), 256, 0, stream>>>(AGKb, QUb, SCAL + 2, QQ / 128, 128, PSBUF);
  k_lse_final2<<<1, 256, 0, stream>>>(PSBUF, 128, LPOSK, KK, LOSS + 1);
  k_loss_add<<<1, 1, 0, stream>>>(LOSS, outLoss);
}

// Round 4
// 579.005 us; speedup vs baseline: 3.4383x; 1.1040x over previous
//
#include <hip/hip_runtime.h>
#include <stdint.h>
#include <math.h>

typedef unsigned int u32;
typedef __attribute__((ext_vector_type(8))) short short8;
typedef __attribute__((ext_vector_type(4))) float f32x4;

#define BB 4096
#define DD 256
#define KK 512
#define LL 32768
#define QQ 8192

// ---------------- Threefry2x32 (JAX-exact, 20 rounds) ----------------
__host__ __device__ inline void tf2x32(u32 k0, u32 k1, u32 c0, u32 c1, u32& o0, u32& o1) {
  u32 ks2 = k0 ^ k1 ^ 0x1BD11BDAu;
  u32 x0 = c0 + k0, x1 = c1 + k1;
#define TF_R(r) { x0 += x1; x1 = ((x1 << (r)) | (x1 >> (32 - (r)))); x1 ^= x0; }
  TF_R(13) TF_R(15) TF_R(26) TF_R(6)
  x0 += k1; x1 += ks2 + 1u;
  TF_R(17) TF_R(29) TF_R(16) TF_R(24)
  x0 += ks2; x1 += k0 + 2u;
  TF_R(13) TF_R(15) TF_R(26) TF_R(6)
  x0 += k0; x1 += k1 + 3u;
  TF_R(17) TF_R(29) TF_R(16) TF_R(24)
  x0 += k1; x1 += ks2 + 4u;
  TF_R(13) TF_R(15) TF_R(26) TF_R(6)
  x0 += ks2; x1 += k0 + 5u;
#undef TF_R
  o0 = x0; o1 = x1;
}

__device__ inline u32 rbits32(u32 k0, u32 k1, u32 i) {
  u32 a, b;
  tf2x32(k0, k1, 0u, i, a, b);
  return a ^ b;
}

__device__ inline float u01f(u32 bits) {
  return __uint_as_float(0x3f800000u | (bits >> 9)) - 1.0f;
}

__device__ inline float gumbel_at(u32 k0, u32 k1, u32 i) {
  float f = u01f(rbits32(k0, k1, i));
  float u = fmaxf(1e-20f, f + 1e-20f);
  float l1 = (float)log((double)u);
  float l2 = (float)log((double)(-l1));
  return -l2;
}

// XLA f32 ErfInv (Giles polynomial)
__device__ inline float erfinv32(float x) {
  float w = -log1pf(-x * x);
  float p;
  if (w < 5.0f) {
    w -= 2.5f;
    p = 2.81022636e-08f;
    p = fmaf(p, w, 3.43273939e-07f);
    p = fmaf(p, w, -3.5233877e-06f);
    p = fmaf(p, w, -4.39150654e-06f);
    p = fmaf(p, w, 0.00021858087f);
    p = fmaf(p, w, -0.00125372503f);
    p = fmaf(p, w, -0.00417768164f);
    p = fmaf(p, w, 0.246640727f);
    p = fmaf(p, w, 1.50140941f);
  } else {
    w = sqrtf(w) - 3.0f;
    p = -0.000200214257f;
    p = fmaf(p, w, 0.000100950558f);
    p = fmaf(p, w, 0.00134934322f);
    p = fmaf(p, w, -0.00367342844f);
    p = fmaf(p, w, 0.00573950773f);
    p = fmaf(p, w, -0.0076224613f);
    p = fmaf(p, w, 0.00943887047f);
    p = fmaf(p, w, 1.00167406f);
    p = fmaf(p, w, 2.83297682f);
  }
  return p * x;
}

__device__ inline unsigned short f2bf(float f) {
  u32 u = __float_as_uint(f);
  u32 r = (u + 0x7FFFu + ((u >> 16) & 1u)) >> 16;
  return (unsigned short)r;
}

// ---------------- Reductions ----------------
__global__ __launch_bounds__(256)
void k_sumsq(const float* __restrict__ x, int n, float* __restrict__ partial) {
  __shared__ float sm[256];
  float s = 0.0f;
  for (int i = blockIdx.x * 256 + threadIdx.x; i < n; i += gridDim.x * 256) {
    float v = x[i]; s = fmaf(v, v, s);
  }
  sm[threadIdx.x] = s; __syncthreads();
  for (int off = 128; off > 0; off >>= 1) {
    if (threadIdx.x < off) sm[threadIdx.x] += sm[threadIdx.x + off];
    __syncthreads();
  }
  if (threadIdx.x == 0) partial[blockIdx.x] = sm[0];
}

__global__ __launch_bounds__(256)
void k_finalize_rsqrt(const float* __restrict__ partial, float* __restrict__ outv) {
  __shared__ float sm[256];
  int tid = threadIdx.x;
  sm[tid] = partial[tid];
  __syncthreads();
  for (int off = 128; off > 0; off >>= 1) {
    if (tid < off) sm[tid] += sm[tid + off];
    __syncthreads();
  }
  if (tid == 0) {
    float ssum = fmaxf(sm[0], 1e-12f);
    outv[0] = (float)(1.0 / sqrt((double)ssum));
  }
}

// ---------------- f32 GEMMs: 64x64 tile, 4x4 register tile ----------------
__global__ __launch_bounds__(256)
void k_gemm_nt64(const float* __restrict__ A, const float* __restrict__ Bm,
                 float* __restrict__ C, int N) {
  __shared__ float As[16][68], Bs[16][68];
  int tid = threadIdx.x;
  int tx = tid & 15, ty = tid >> 4;
  int rowBase = blockIdx.y * 64, colBase = blockIdx.x * 64;
  float c[4][4] = {};
  for (int kt = 0; kt < 256; kt += 16) {
#pragma unroll
    for (int q = 0; q < 4; q++) {
      int idx = tid + 256 * q;
      int kkx = idx & 15, rr = idx >> 4;
      As[kkx][rr] = A[(size_t)(rowBase + rr) * 256 + kt + kkx];
      Bs[kkx][rr] = Bm[(size_t)(colBase + rr) * 256 + kt + kkx];
    }
    __syncthreads();
#pragma unroll
    for (int kx = 0; kx < 16; kx++) {
      float4 a4 = *(const float4*)&As[kx][ty * 4];
      float4 b4 = *(const float4*)&Bs[kx][tx * 4];
      float av[4] = {a4.x, a4.y, a4.z, a4.w};
      float bv[4] = {b4.x, b4.y, b4.z, b4.w};
#pragma unroll
      for (int r = 0; r < 4; r++)
#pragma unroll
        for (int q = 0; q < 4; q++)
          c[r][q] = fmaf(av[r], bv[q], c[r][q]);
    }
    __syncthreads();
  }
#pragma unroll
  for (int r = 0; r < 4; r++)
#pragma unroll
    for (int q = 0; q < 4; q++)
      C[(size_t)(rowBase + ty * 4 + r) * N + colBase + tx * 4 + q] = c[r][q];
}

// C[M x N] = A[M x K] * Bm[K x N]; grid (N/64, M/64, S)
__global__ __launch_bounds__(256)
void k_gemm_nn64(const float* __restrict__ A, const float* __restrict__ Bm,
                 float* __restrict__ C, int N, int K, int M, int Kc) {
  __shared__ float As[16][68], Bs[16][68];
  int tid = threadIdx.x;
  int tx = tid & 15, ty = tid >> 4;
  int rowBase = blockIdx.y * 64, colBase = blockIdx.x * 64;
  int k0 = blockIdx.z * Kc;
  float c[4][4] = {};
  for (int kt = k0; kt < k0 + Kc; kt += 16) {
#pragma unroll
    for (int q = 0; q < 4; q++) {
      int idx = tid + 256 * q;
      int kkx = idx & 15, rr = idx >> 4;
      As[kkx][rr] = A[(size_t)(rowBase + rr) * K + kt + kkx];
      int kk = (tid >> 6) * 4 + q;
      int jj = tid & 63;
      Bs[kk][jj] = Bm[(size_t)(kt + kk) * N + colBase + jj];
    }
    __syncthreads();
#pragma unroll
    for (int kx = 0; kx < 16; kx++) {
      float4 a4 = *(const float4*)&As[kx][ty * 4];
      float4 b4 = *(const float4*)&Bs[kx][tx * 4];
      float av[4] = {a4.x, a4.y, a4.z, a4.w};
      float bv[4] = {b4.x, b4.y, b4.z, b4.w};
#pragma unroll
      for (int r = 0; r < 4; r++)
#pragma unroll
        for (int q = 0; q < 4; q++)
          c[r][q] = fmaf(av[r], bv[q], c[r][q]);
    }
    __syncthreads();
  }
  float* dst = C + (size_t)blockIdx.z * M * N;
#pragma unroll
  for (int r = 0; r < 4; r++)
#pragma unroll
    for (int q = 0; q < 4; q++)
      dst[(size_t)(rowBase + ty * 4 + r) * N + colBase + tx * 4 + q] = c[r][q];
}

__global__ __launch_bounds__(256)
void k_reduce_div(const float* __restrict__ Cp, int S, int MN,
                  const float* __restrict__ rs, float* __restrict__ out) {
  int i = blockIdx.x * 256 + threadIdx.x;
  if (i >= MN) return;
  float s = 0.0f;
  for (int t = 0; t < S; t++) s += Cp[(size_t)t * MN + i];
  out[i] = s / (rs[i >> 8] + 1e-8f);
}

// ---------------- softmax(y1) + hard argmax(y2), wave-shuffle reductions ----------------
__global__ __launch_bounds__(256)
void k_softmax_assign(const float* __restrict__ knT, float* __restrict__ Y,
                      float* __restrict__ assignOut,
                      u32 g1a, u32 g1b, u32 g2a, u32 g2b) {
  __shared__ float smA[4], smS[4], smM2[4], smS2[4], smV[4];
  __shared__ int smI[4];
  int b = blockIdx.x, tid = threadIdx.x;
  int lane = tid & 63, wid = tid >> 6;
  int i0 = b * KK + tid, i1 = i0 + 256;
  float x0 = knT[i0], x1 = knT[i1];

  // soft assignment y1
  float z0 = x0 + gumbel_at(g1a, g1b, (u32)i0);
  float z1 = x1 + gumbel_at(g1a, g1b, (u32)i1);
  float wm = fmaxf(z0, z1);
#pragma unroll
  for (int off = 1; off < 64; off <<= 1) wm = fmaxf(wm, __shfl_xor(wm, off, 64));
  if (lane == 0) smA[wid] = wm;
  __syncthreads();
  float m = fmaxf(fmaxf(smA[0], smA[1]), fmaxf(smA[2], smA[3]));
  float e0 = expf(z0 - m), e1 = expf(z1 - m);
  float ws = e0 + e1;
#pragma unroll
  for (int off = 1; off < 64; off <<= 1) ws += __shfl_xor(ws, off, 64);
  if (lane == 0) smS[wid] = ws;
  __syncthreads();
  float s = (smS[0] + smS[1]) + (smS[2] + smS[3]);
  Y[i0] = e0 / s;
  Y[i1] = e1 / s;

  if (assignOut != nullptr) {
    float w0 = x0 + gumbel_at(g2a, g2b, (u32)i0);
    float w1 = x1 + gumbel_at(g2a, g2b, (u32)i1);
    float wm2 = fmaxf(w0, w1);
#pragma unroll
    for (int off = 1; off < 64; off <<= 1) wm2 = fmaxf(wm2, __shfl_xor(wm2, off, 64));
    if (lane == 0) smM2[wid] = wm2;
    __syncthreads();
    float m2 = fmaxf(fmaxf(smM2[0], smM2[1]), fmaxf(smM2[2], smM2[3]));
    float f0 = expf(w0 - m2), f1 = expf(w1 - m2);
    float ws2 = f0 + f1;
#pragma unroll
    for (int off = 1; off < 64; off <<= 1) ws2 += __shfl_xor(ws2, off, 64);
    if (lane == 0) smS2[wid] = ws2;
    __syncthreads();
    float s2 = (smS2[0] + smS2[1]) + (smS2[2] + smS2[3]);
    float y0 = f0 / s2, y1v = f1 / s2;
    float bv; int bi;
    if (y1v > y0) { bv = y1v; bi = tid + 256; } else { bv = y0; bi = tid; }
#pragma unroll
    for (int off = 1; off < 64; off <<= 1) {
      float ov = __shfl_xor(bv, off, 64);
      int oi = __shfl_xor(bi, off, 64);
      if (ov > bv || (ov == bv && oi < bi)) { bv = ov; bi = oi; }
    }
    if (lane == 0) { smV[wid] = bv; smI[wid] = bi; }
    __syncthreads();
    if (tid == 0) {
      float cv = smV[0]; int ci = smI[0];
#pragma unroll
      for (int t = 1; t < 4; t++) {
        if (smV[t] > cv || (smV[t] == cv && smI[t] < ci)) { cv = smV[t]; ci = smI[t]; }
      }
      assignOut[b] = (float)ci;
    }
  }
}

// ---------------- stochastic binary threshold ----------------
__global__ __launch_bounds__(256)
void k_binary(const float* __restrict__ knT, float* __restrict__ BIN, u32 k3a, u32 k3b) {
  int i = blockIdx.x * 256 + threadIdx.x;
  if (i >= KK * BB) return;
  int k = i / BB, b = i - k * BB;
  float x = knT[b * KK + k];
  float prob = (float)(1.0 / (1.0 + exp(-(double)x)));
  float eps = u01f(rbits32(k3a, k3b, (u32)i));
  BIN[i] = (prob > eps) ? 1.0f : 0.0f;
}

__global__ __launch_bounds__(256)
void k_rowsum(const float* __restrict__ BIN, float* __restrict__ rs) {
  __shared__ float sm[256];
  int k = blockIdx.x, tid = threadIdx.x;
  float s = 0.0f;
  for (int b = tid; b < BB; b += 256) s += BIN[k * BB + b];
  sm[tid] = s; __syncthreads();
  for (int off = 128; off > 0; off >>= 1) {
    if (tid < off) sm[tid] += sm[tid + off];
    __syncthreads();
  }
  if (tid == 0) rs[k] = sm[0];
}

__global__ __launch_bounds__(256)
void k_scale(float* __restrict__ x, const float* __restrict__ fac, int n) {
  int i = blockIdx.x * 256 + threadIdx.x;
  if (i < n) x[i] = x[i] * fac[0];
}

// ---------------- queue = 2*qk + 0.1*normal ----------------
__global__ __launch_bounds__(256)
void k_queue(const float* __restrict__ qk_in, const float* __restrict__ skp,
             float* __restrict__ QUEUE, u32 kqa, u32 kqb) {
  int i = blockIdx.x * 256 + threadIdx.x;
  if (i >= QQ * DD) return;
  float sk = skp[0];
  float qk = qk_in[i] * sk;
  float f = u01f(rbits32(kqa, kqb, (u32)i));
  const float lo = -0.99999994f;
  float u = fmaxf(lo, f * 2.0f + lo);
  float nv = 1.41421354f * erfinv32(u);
  float t = qk + 0.1f * nv;
  QUEUE[i] = t + qk;
}

__global__ __launch_bounds__(256)
void k_rowdot(const float* __restrict__ A, const float* __restrict__ Bv, float* __restrict__ outv) {
  __shared__ float sm[256];
  int r = blockIdx.x, tid = threadIdx.x;
  sm[tid] = A[r * 256 + tid] * Bv[r * 256 + tid];
  __syncthreads();
  for (int off = 128; off > 0; off >>= 1) {
    if (tid < off) sm[tid] += sm[tid + off];
    __syncthreads();
  }
  if (tid == 0) outv[r] = sm[0];
}

// ---------------- f32 -> bf16 conversion ----------------
__global__ __launch_bounds__(256)
void k_cvt_bf16(const float* __restrict__ src, unsigned short* __restrict__ dst, int n) {
  int i = (blockIdx.x * 256 + threadIdx.x) * 4;
  if (i >= n) return;
  float4 v = *(const float4*)(src + i);
  ushort2 a, b;
  a.x = f2bf(v.x); a.y = f2bf(v.y);
  b.x = f2bf(v.z); b.y = f2bf(v.w);
  *(ushort2*)(dst + i) = a;
  *(ushort2*)(dst + i + 2) = b;
}

// ---------------- fused bf16-MFMA GEMM + sum-exp (fixed m=0) ----------------
// |logits| < 0.01 (globally-l2-normalized operands), so sum-exp needs no max.
// grid (M/256, nsplit), block 256 = 4 waves; wave owns 64 rows (4 A-tilesets).
// ps layout: [nsplit][M] (split-major -> coalesced in k_lse_partial).
__global__ __launch_bounds__(256)
void k_lse_mfma2(const unsigned short* __restrict__ Qb, const unsigned short* __restrict__ Nb,
                 const float* __restrict__ scale_ptr, int Lper, int M,
                 float* __restrict__ ps) {
  int tid = threadIdx.x;
  int wave = tid >> 6, lane = tid & 63;
  int rowBase = blockIdx.x * 256 + wave * 64;
  int j0 = blockIdx.y * Lper;
  float lsc = scale_ptr[0] / 0.07f;
  int lr = lane & 15;
  int lk = (lane >> 4) * 8;

  short8 afr[4][8];
#pragma unroll
  for (int ts = 0; ts < 4; ts++)
#pragma unroll
    for (int kf = 0; kf < 8; kf++)
      afr[ts][kf] = *(const short8*)(Qb + (size_t)(rowBase + ts * 16 + lr) * 256 + kf * 32 + lk);

  float s[4][4];
#pragma unroll
  for (int ts = 0; ts < 4; ts++)
#pragma unroll
    for (int r = 0; r < 4; r++) s[ts][r] = 0.0f;

#pragma unroll 2
  for (int j = 0; j < Lper; j += 16) {
    const unsigned short* bbase = Nb + (size_t)(j0 + j + lr) * 256 + lk;
    short8 bfr[8];
#pragma unroll
    for (int kf = 0; kf < 8; kf++) bfr[kf] = *(const short8*)(bbase + kf * 32);
#pragma unroll
    for (int ts = 0; ts < 4; ts++) {
      f32x4 acc = {0.f, 0.f, 0.f, 0.f};
#pragma unroll
      for (int kf = 0; kf < 8; kf++)
        acc = __builtin_amdgcn_mfma_f32_16x16x32_bf16(afr[ts][kf], bfr[kf], acc, 0, 0, 0);
#pragma unroll
      for (int r = 0; r < 4; r++)
        s[ts][r] += __expf(acc[r] * lsc);
    }
  }
#pragma unroll
  for (int off = 1; off < 16; off <<= 1)
#pragma unroll
    for (int ts = 0; ts < 4; ts++)
#pragma unroll
      for (int r = 0; r < 4; r++)
        s[ts][r] += __shfl_xor(s[ts][r], off, 64);
  if (lr == 0) {
    int rg = (lane >> 4) * 4;
#pragma unroll
    for (int ts = 0; ts < 4; ts++)
#pragma unroll
      for (int r = 0; r < 4; r++)
        ps[(size_t)blockIdx.y * M + rowBase + ts * 16 + rg + r] = s[ts][r];
  }
}

// partial row-LSE sums: grid nb blocks, one row per thread (M = nb*256)
__global__ __launch_bounds__(256)
void k_lse_partial(const float* __restrict__ ps, int nsplit,
                   const float* __restrict__ lpos, int M, float* __restrict__ partial) {
  __shared__ float sm[256];
  int tid = threadIdx.x;
  int row = blockIdx.x * 256 + tid;
  float s = 0.0f;
  for (int t = 0; t < nsplit; t++) s += ps[(size_t)t * M + row];
  float z0 = lpos[row] / 0.07f;
  s += expf(z0);
  float acc = logf(s) - z0;
  sm[tid] = acc; __syncthreads();
  for (int off = 128; off > 0; off >>= 1) {
    if (tid < off) sm[tid] += sm[tid + off];
    __syncthreads();
  }
  if (tid == 0) partial[blockIdx.x] = sm[0];
}

__global__ void k_loss_merge(const float* __restrict__ PN, int nN, int MN,
                             const float* __restrict__ PK, int nK, int MK,
                             float* __restrict__ outLoss) {
  if (threadIdx.x == 0) {
    float a = 0.0f, b = 0.0f;
    for (int i = 0; i < nN; i++) a += PN[i];
    for (int i = 0; i < nK; i++) b += PK[i];
    outLoss[0] = a / (float)MN + b / (float)MK;
  }
}

// ---------------- launch ----------------
extern "C" void kernel_launch(void* const* d_in, const int* in_sizes, int n_in,
                              void* d_out, int out_size, void* d_ws, size_t ws_size,
                              hipStream_t stream) {
  const float* feat[2] = {(const float*)d_in[0], (const float*)d_in[1]};
  const float* ctx[2]  = {(const float*)d_in[2], (const float*)d_in[3]};
  const float* queue_n = (const float*)d_in[4];
  const float* queue_k = (const float*)d_in[5];

  float* W = (float*)d_ws;
  size_t o = 0;
  float* T     = W + o; o += (size_t)BB * KK;
  float* Yb    = W + o; o += (size_t)BB * KK;   // also split-K partials (CP)
  float* BIN   = W + o; o += (size_t)KK * BB;
  float* AGGN1 = W + o; o += (size_t)BB * DD;
  float* AGGK1 = W + o; o += (size_t)KK * DD;
  float* QUEUE = W + o; o += (size_t)QQ * DD;
  float* RS    = W + o; o += KK;
  float* PART  = W + o; o += 256;
  float* SCAL  = W + o; o += 8;
  float* LPOSN = W + o; o += BB;
  float* LPOSK = W + o; o += KK;
  float* PNp   = W + o; o += 32;
  float* PKp   = W + o; o += 32;

  // bf16 loss operands overlay the dead T/Yb/BIN region
  unsigned short* QNb  = (unsigned short*)T;                 // 32768*256
  unsigned short* QUb  = QNb + (size_t)LL * DD;              // 8192*256
  unsigned short* AGNb = QUb + (size_t)QQ * DD;              // 4096*256
  unsigned short* AGKb = AGNb + (size_t)BB * DD;             // 512*256
  // PSBUF lives in the leftover tail of BIN (1.83 MB free; max need 1.0 MB)
  float* PSBUF = (float*)(AGKb + (size_t)KK * DD);
  float* CP = Yb;                                            // split-K partials

  float* out = (float*)d_out;
  float* outAssign = out;
  float* outAggn2  = out + BB;
  float* outAggk2  = out + BB + (size_t)BB * DD;
  float* outLoss   = out + BB + (size_t)BB * DD + (size_t)KK * DD;

  u32 kq0, kq1, kc[2][2];
  tf2x32(0u, 42u, 0u, 0u, kq0, kq1);
  tf2x32(0u, 42u, 0u, 1u, kc[0][0], kc[0][1]);
  tf2x32(0u, 42u, 0u, 2u, kc[1][0], kc[1][1]);
  u32 sub[2][3][2];
  for (int br = 0; br < 2; br++)
    for (int t = 0; t < 3; t++)
      tf2x32(kc[br][0], kc[br][1], 0u, (u32)t, sub[br][t][0], sub[br][t][1]);

  k_sumsq<<<256, 256, 0, stream>>>(queue_n, LL * DD, PART);
  k_finalize_rsqrt<<<1, 256, 0, stream>>>(PART, SCAL + 0);   // sn
  k_sumsq<<<256, 256, 0, stream>>>(queue_k, QQ * DD, PART);
  k_finalize_rsqrt<<<1, 256, 0, stream>>>(PART, SCAL + 1);   // sk

  for (int br = 0; br < 2; br++) {
    float* aggn = (br == 0) ? AGGN1 : outAggn2;
    float* aggk = (br == 0) ? AGGK1 : outAggk2;
    k_gemm_nt64<<<dim3(KK / 64, BB / 64), 256, 0, stream>>>(feat[br], ctx[br], T, KK);
    k_softmax_assign<<<BB, 256, 0, stream>>>(T, Yb, br == 0 ? outAssign : nullptr,
        sub[br][0][0], sub[br][0][1], sub[br][1][0], sub[br][1][1]);
    k_binary<<<(KK * BB) / 256, 256, 0, stream>>>(T, BIN, sub[br][2][0], sub[br][2][1]);
    k_rowsum<<<KK, 256, 0, stream>>>(BIN, RS);
    k_gemm_nn64<<<dim3(DD / 64, BB / 64, 1), 256, 0, stream>>>(Yb, ctx[br], aggn, DD, KK, BB, KK);
    k_gemm_nn64<<<dim3(DD / 64, KK / 64, 8), 256, 0, stream>>>(BIN, feat[br], CP, DD, BB, KK, 512);
    k_reduce_div<<<(KK * DD) / 256, 256, 0, stream>>>(CP, 8, KK * DD, RS, aggk);
    k_sumsq<<<256, 256, 0, stream>>>(aggn, BB * DD, PART);
    k_finalize_rsqrt<<<1, 256, 0, stream>>>(PART, SCAL + 3);
    k_scale<<<(BB * DD) / 256, 256, 0, stream>>>(aggn, SCAL + 3, BB * DD);
    k_sumsq<<<256, 256, 0, stream>>>(aggk, KK * DD, PART);
    k_finalize_rsqrt<<<1, 256, 0, stream>>>(PART, SCAL + 4);
    k_scale<<<(KK * DD) / 256, 256, 0, stream>>>(aggk, SCAL + 4, KK * DD);
  }

  k_queue<<<(QQ * DD) / 256, 256, 0, stream>>>(queue_k, SCAL + 1, QUEUE, kq0, kq1);
  k_sumsq<<<256, 256, 0, stream>>>(QUEUE, QQ * DD, PART);
  k_finalize_rsqrt<<<1, 256, 0, stream>>>(PART, SCAL + 2);   // fq

  // positives (f32)
  k_rowdot<<<BB, 256, 0, stream>>>(AGGN1, outAggn2, LPOSN);
  k_rowdot<<<KK, 256, 0, stream>>>(AGGK1, outAggk2, LPOSK);

  // bf16 conversions (T/Yb/BIN dead from here)
  k_cvt_bf16<<<(LL * DD) / 1024, 256, 0, stream>>>(queue_n, QNb, LL * DD);
  k_cvt_bf16<<<(QQ * DD) / 1024, 256, 0, stream>>>(QUEUE, QUb, QQ * DD);
  k_cvt_bf16<<<(BB * DD) / 1024, 256, 0, stream>>>(AGGN1, AGNb, BB * DD);
  k_cvt_bf16<<<(KK * DD) / 1024, 256, 0, stream>>>(AGGK1, AGKb, KK * DD);

  // loss_n: q = agg_n_1, negs = queue_n (sn folded into logit scale). nsplit=64.
  k_lse_mfma2<<<dim3(BB / 256, 64), 256, 0, stream>>>(AGNb, QNb, SCAL + 0, LL / 64, BB, PSBUF);
  k_lse_partial<<<BB / 256, 256, 0, stream>>>(PSBUF, 64, LPOSN, BB, PNp);
  // loss_k: q = agg_k_1, negs = QUEUE (fq folded into logit scale). nsplit=128.
  k_lse_mfma2<<<dim3(KK / 256, 128), 256, 0, stream>>>(AGKb, QUb, SCAL + 2, QQ / 128, KK, PSBUF);
  k_lse_partial<<<KK / 256, 256, 0, stream>>>(PSBUF, 128, LPOSK, KK, PKp);
  k_loss_merge<<<1, 64, 0, stream>>>(PNp, BB / 256, BB, PKp, KK / 256, KK, outLoss);
}